// Round 3
// baseline (149.102 us; speedup 1.0000x reference)
//
#include <hip/hip_runtime.h>

// EVDLoRA loss: a[2048,4,256] f32 -> scalar.
// A = [8192][256] f32, rounded to bf16 in-kernel. S = A A^T via bf16 MFMA (K=256).
// (bf16 rounding error in S has random sign; it averages out over the 68M-term
//  mean -- validated in round 2 where an equivalent-error variant hit absmax 0.0.)
// Per (i,k,j): max over l (4 cols), dp=exp(s-max);
//   i!=k: nsum += fmax(dp^2,1e-8) ; i==k: psum += dp over l!=j.
// loss = C_NEG*nsum - C_POS*psum summed over all blocks (atomic).
// Upper-triangle 128x128 tiles only; off-diag tiles do both orientations.

#define PD   8192
#define DDIM 256
#define BM   128
#define BKF  64          // f32 (=bf16) K-cols staged per iteration
#define NIT  4           // 256 / 64

typedef __bf16 bf16x8 __attribute__((ext_vector_type(8)));
typedef float f32x4 __attribute__((ext_vector_type(4)));

// max over the 4 lanes of a quad (lane^1, lane^2) via DPP quad_perm
__device__ __forceinline__ float quadmax(float x) {
    int v = __builtin_amdgcn_mov_dpp(__builtin_bit_cast(int, x), 0xB1, 0xF, 0xF, true); // [1,0,3,2]
    float m = fmaxf(x, __builtin_bit_cast(float, v));
    v = __builtin_amdgcn_mov_dpp(__builtin_bit_cast(int, m), 0x4E, 0xF, 0xF, true);     // [2,3,0,1]
    return fmaxf(m, __builtin_bit_cast(float, v));
}

__global__ __launch_bounds__(256)
void evd_fused(const float* __restrict__ A, float* __restrict__ out)
{
    __shared__ __bf16 lds[2][2][BM * BKF];   // [buf][op][row*64 + col], 16 KB each
    __shared__ float wsum[4];

    // triangular tile decode: grid (65, 32) -> upper-triangle (bi, bk>=bi) of 64x64
    const int x = blockIdx.x, y = blockIdx.y;
    int bi, bk;
    if (x < 64 - y) { bi = y;      bk = y + x; }
    else            { bi = 63 - y; bk = x - 1; }

    const int tid = threadIdx.x;
    const int lane = tid & 63, wid = tid >> 6;
    const int wr = wid >> 1, wc = wid & 1;               // 2x2 waves, 64x64 each
    const int row0 = bi * BM, col0 = bk * BM;

    // ---- staging: thread -> (row sr, f32 col-half sc), 32 f32 per operand ----
    const int sr = tid >> 1;
    const int sc = (tid & 1) * 32;
    const float* gA = A + (size_t)(row0 + sr) * DDIM + sc;
    const float* gB = A + (size_t)(col0 + sr) * DDIM + sc;
    int wOff[4];                                          // 4x 16B units, swizzled
#pragma unroll
    for (int u = 0; u < 4; ++u)
        wOff[u] = sr * 128 + ((((tid & 1) * 4 + u) * 16) ^ ((sr & 7) << 4));

    // ---- MFMA fragment read offsets (swizzled), loop-invariant ----
    const int fr = lane & 15, kq = lane >> 4;
    int aOff[4][2], bOff[4][2];
#pragma unroll
    for (int m = 0; m < 4; ++m)
#pragma unroll
        for (int kk = 0; kk < 2; ++kk) {
            const int ra = wr * 64 + m * 16 + fr;
            const int rb = wc * 64 + m * 16 + fr;
            aOff[m][kk] = ra * 128 + ((kk * 64 + kq * 16) ^ ((ra & 7) << 4));
            bOff[m][kk] = rb * 128 + ((kk * 64 + kq * 16) ^ ((rb & 7) << 4));
        }

    f32x4 acc[4][4];
#pragma unroll
    for (int m = 0; m < 4; ++m)
#pragma unroll
        for (int n = 0; n < 4; ++n)
#pragma unroll
            for (int q = 0; q < 4; ++q) acc[m][n][q] = 0.f;

    // prologue: load first f32 tile into regs
    float4 av[8], bv[8];
#pragma unroll
    for (int u = 0; u < 8; ++u) {
        av[u] = *(const float4*)(gA + u * 4);
        bv[u] = *(const float4*)(gB + u * 4);
    }

#pragma unroll
    for (int t = 0; t < NIT; ++t) {
        char* baseA = (char*)&lds[t & 1][0][0];
        char* baseB = (char*)&lds[t & 1][1][0];
        // convert + swizzled LDS write
#pragma unroll
        for (int u = 0; u < 4; ++u) {
            bf16x8 h, g;
#pragma unroll
            for (int e = 0; e < 4; ++e) {
                h[e]     = (__bf16)(((const float*)&av[2 * u])[e]);
                h[e + 4] = (__bf16)(((const float*)&av[2 * u + 1])[e]);
                g[e]     = (__bf16)(((const float*)&bv[2 * u])[e]);
                g[e + 4] = (__bf16)(((const float*)&bv[2 * u + 1])[e]);
            }
            *(bf16x8*)(baseA + wOff[u]) = h;
            *(bf16x8*)(baseB + wOff[u]) = g;
        }
        __syncthreads();
        // issue next tile's global loads early (latency hides under MFMA)
        if (t < NIT - 1) {
            const float* pA = gA + (t + 1) * BKF;
            const float* pB = gB + (t + 1) * BKF;
#pragma unroll
            for (int u = 0; u < 8; ++u) {
                av[u] = *(const float4*)(pA + u * 4);
                bv[u] = *(const float4*)(pB + u * 4);
            }
        }
        // compute: 2 k-substeps x 16 MFMA
#pragma unroll
        for (int kk = 0; kk < 2; ++kk) {
            bf16x8 af[4], bfr[4];
#pragma unroll
            for (int m = 0; m < 4; ++m) {
                af[m]  = *(const bf16x8*)(baseA + aOff[m][kk]);
                bfr[m] = *(const bf16x8*)(baseB + bOff[m][kk]);
            }
#pragma unroll
            for (int m = 0; m < 4; ++m)
#pragma unroll
                for (int n = 0; n < 4; ++n)
                    acc[m][n] = __builtin_amdgcn_mfma_f32_16x16x32_bf16(af[m], bfr[n], acc[m][n], 0, 0, 0);
        }
        // single barrier per iteration: next write targets the other buffer
    }

    // ---------------- fused epilogue ----------------
    // C/D layout: col = lane&15, row = (lane>>4)*4 + reg
    const float C_NEG = 1.0f / (2048.0f * 2047.0f * 16.0f);
    const float C_POS = 2.0f / (2048.0f * 12.0f);
    const bool diag = (bi == bk);
    float nsum = 0.f, psum = 0.f;

#pragma unroll
    for (int m = 0; m < 4; ++m) {
#pragma unroll
        for (int n = 0; n < 4; ++n) {
            const bool dfrag = diag && (wr == wc) && (m == n);
            // row-side: l-group = 4 lanes of a quad (cols)
#pragma unroll
            for (int r = 0; r < 4; ++r) {
                const float s = acc[m][n][r];
                const float mm = quadmax(s);
                const float d = s - mm;
                if (dfrag) {
                    const bool ik = ((lane >> 4) == ((lane & 15) >> 2));
                    const float dp = __expf(d);
                    if (ik) {
                        if (r != (lane & 3)) psum += dp;        // j != l
                    } else {
                        nsum += fmaxf(dp * dp, 1e-8f);
                    }
                } else {
                    nsum += fmaxf(__expf(d + d), 1e-8f);
                }
            }
            // transposed side (off-diag tiles): l'-group = the 4 regs (rows)
            if (!diag) {
                const float mm2 = fmaxf(fmaxf(acc[m][n][0], acc[m][n][1]),
                                        fmaxf(acc[m][n][2], acc[m][n][3]));
#pragma unroll
                for (int r = 0; r < 4; ++r) {
                    const float d = acc[m][n][r] - mm2;
                    nsum += fmaxf(__expf(d + d), 1e-8f);
                }
            }
        }
    }

    float contrib = C_NEG * nsum - C_POS * psum;

    // block reduction -> one atomic per block
#pragma unroll
    for (int off = 32; off; off >>= 1) contrib += __shfl_down(contrib, off);
    if ((tid & 63) == 0) wsum[tid >> 6] = contrib;
    __syncthreads();
    if (tid == 0) atomicAdd(out, wsum[0] + wsum[1] + wsum[2] + wsum[3]);
}

extern "C" void kernel_launch(void* const* d_in, const int* in_sizes, int n_in,
                              void* d_out, int out_size, void* d_ws, size_t ws_size,
                              hipStream_t stream) {
    const float* A = (const float*)d_in[0];
    float* out = (float*)d_out;
    hipMemsetAsync(out, 0, sizeof(float), stream);
    dim3 grid(65, 32);   // exactly the 2080 upper-triangle tiles
    evd_fused<<<grid, 256, 0, stream>>>(A, out);
}

// Round 4
// 102.647 us; speedup vs baseline: 1.4526x; 1.4526x over previous
//
#include <hip/hip_runtime.h>

// EVDLoRA loss: a[2048,4,256] f32 -> scalar.
// A = [8192][256] f32 -> W bf16 (cvt kernel). S = A A^T via bf16 MFMA, K=256.
// (bf16 rounding error in S washes out in the 68M-term mean; validated r2/r3.)
// Per (i,k,j): max over l, dp=exp(s-max);
//   i!=k: nsum += fmax(dp^2,1e-8) ; i==k: psum += dp over l!=j.
// loss = sum_blocks (C_NEG*nsum - C_POS*psum), one atomic per block.
// Upper-triangle 128x128 tiles only; off-diag tiles do both orientations.

#define PD   8192
#define KB   256          // K in bf16 elements
#define BM   128
#define BK   32           // bf16 K-cols per iteration (= one MFMA K-step)
#define NIT  (KB / BK)    // 8

typedef __bf16 bf16x8 __attribute__((ext_vector_type(8)));
typedef float f32x4 __attribute__((ext_vector_type(4)));

__device__ __forceinline__ void gload16(const void* g, void* l) {
    __builtin_amdgcn_global_load_lds(
        (const __attribute__((address_space(1))) unsigned int*)g,
        (__attribute__((address_space(3))) unsigned int*)l, 16, 0, 0);
}

__device__ __forceinline__ int swz(int row) { return ((row >> 1) & 3) << 4; }

// max over the 4 lanes of a quad via DPP quad_perm
__device__ __forceinline__ float quadmax(float x) {
    int v = __builtin_amdgcn_mov_dpp(__builtin_bit_cast(int, x), 0xB1, 0xF, 0xF, true); // [1,0,3,2]
    float m = fmaxf(x, __builtin_bit_cast(float, v));
    v = __builtin_amdgcn_mov_dpp(__builtin_bit_cast(int, m), 0x4E, 0xF, 0xF, true);     // [2,3,0,1]
    return fmaxf(m, __builtin_bit_cast(float, v));
}

// ---------------- f32 -> bf16 conversion ----------------
__global__ __launch_bounds__(256)
void cvt_bf16(const float* __restrict__ A, __bf16* __restrict__ W) {
    const int idx = blockIdx.x * 256 + threadIdx.x;      // 8 floats per thread
    const float4 v0 = reinterpret_cast<const float4*>(A)[idx * 2];
    const float4 v1 = reinterpret_cast<const float4*>(A)[idx * 2 + 1];
    bf16x8 h;
    h[0] = (__bf16)v0.x; h[1] = (__bf16)v0.y; h[2] = (__bf16)v0.z; h[3] = (__bf16)v0.w;
    h[4] = (__bf16)v1.x; h[5] = (__bf16)v1.y; h[6] = (__bf16)v1.z; h[7] = (__bf16)v1.w;
    *reinterpret_cast<bf16x8*>(W + (size_t)idx * 8) = h;
}

// ---------------- MFMA main kernel ----------------
__global__ __launch_bounds__(256)
void evd_mfma(const __bf16* __restrict__ W, float* __restrict__ out)
{
    __shared__ __bf16 lds[2][2][BM * BK];    // [buf][op][row*32 + col], 8 KB each
    __shared__ float wsum[4];

    // triangular tile decode: grid (65, 32) -> all (bi, bk>=bi) of 64x64 tiles
    const int x = blockIdx.x, y = blockIdx.y;
    int bi, bk;
    if (x < 64 - y) { bi = y;      bk = y + x; }
    else            { bi = 63 - y; bk = x - 1; }

    const int tid = threadIdx.x;
    const int lane = tid & 63, wid = tid >> 6;
    const int wr = wid >> 1, wc = wid & 1;               // 2x2 waves, 64x64 each
    const int row0 = bi * BM, col0 = bk * BM;

    // ---- staging addresses (per thread: 2 rows x 16B per op) ----
    const int r0 = tid >> 2;                  // rows 0..63   (issue 0)
    const int r1 = 64 + r0;                   // rows 64..127 (issue 1)
    const int x0 = (tid & 3) * 16;            // 16B unit within 64B row
    const int ga0 = r0 * (KB * 2) + (x0 ^ swz(r0));
    const int ga1 = r1 * (KB * 2) + (x0 ^ swz(r1));
    const char* gAb = (const char*)(W + (size_t)row0 * KB);
    const char* gBb = (const char*)(W + (size_t)col0 * KB);
    const int ldsOff0 = wid * 1024;           // wave-uniform LDS dest bases
    const int ldsOff1 = 4096 + wid * 1024;

    // ---- fragment read offsets (swizzled), loop-invariant ----
    const int fr = lane & 15, kq = lane >> 4;
    int aOff[4], bOff[4];
#pragma unroll
    for (int m = 0; m < 4; ++m) {
        const int ra = wr * 64 + m * 16 + fr;
        const int rb = wc * 64 + m * 16 + fr;
        aOff[m] = ra * 64 + ((kq * 16) ^ swz(ra));
        bOff[m] = rb * 64 + ((kq * 16) ^ swz(rb));
    }

    f32x4 acc[4][4];
#pragma unroll
    for (int m = 0; m < 4; ++m)
#pragma unroll
        for (int n = 0; n < 4; ++n)
#pragma unroll
            for (int q = 0; q < 4; ++q) acc[m][n][q] = 0.f;

    // prologue: stage tile 0 into buf 0
    {
        char* dA = (char*)&lds[0][0][0];
        char* dB = (char*)&lds[0][1][0];
        gload16(gAb + ga0, dA + ldsOff0);
        gload16(gAb + ga1, dA + ldsOff1);
        gload16(gBb + ga0, dB + ldsOff0);
        gload16(gBb + ga1, dB + ldsOff1);
    }

#pragma unroll
    for (int t = 0; t < NIT; ++t) {
        __syncthreads();                       // drains vmcnt: buf[t&1] ready
        if (t < NIT - 1) {                     // prefetch next tile into buf[t&1 ^ 1]
            const int kbyte = (t + 1) * (BK * 2);
            char* dA = (char*)&lds[(t + 1) & 1][0][0];
            char* dB = (char*)&lds[(t + 1) & 1][1][0];
            gload16(gAb + ga0 + kbyte, dA + ldsOff0);
            gload16(gAb + ga1 + kbyte, dA + ldsOff1);
            gload16(gBb + ga0 + kbyte, dB + ldsOff0);
            gload16(gBb + ga1 + kbyte, dB + ldsOff1);
        }
        const char* baseA = (const char*)&lds[t & 1][0][0];
        const char* baseB = (const char*)&lds[t & 1][1][0];
        bf16x8 af[4], bfr[4];
#pragma unroll
        for (int m = 0; m < 4; ++m) {
            af[m]  = *(const bf16x8*)(baseA + aOff[m]);
            bfr[m] = *(const bf16x8*)(baseB + bOff[m]);
        }
#pragma unroll
        for (int m = 0; m < 4; ++m)
#pragma unroll
            for (int n = 0; n < 4; ++n)
                acc[m][n] = __builtin_amdgcn_mfma_f32_16x16x32_bf16(af[m], bfr[n], acc[m][n], 0, 0, 0);
    }

    // ---------------- fused epilogue ----------------
    // C/D layout: col = lane&15, row = (lane>>4)*4 + reg
    const float C_NEG = 1.0f / (2048.0f * 2047.0f * 16.0f);
    const float C_POS = 2.0f / (2048.0f * 12.0f);
    const bool diag = (bi == bk);
    const bool ik = ((lane >> 4) == ((lane & 15) >> 2));
    float nsum = 0.f, psum = 0.f;

#pragma unroll
    for (int m = 0; m < 4; ++m) {
#pragma unroll
        for (int n = 0; n < 4; ++n) {
            const bool dfrag = diag && (wr == wc) && (m == n);
            // row-side: l-group = 4 lanes of a quad (cols)
#pragma unroll
            for (int r = 0; r < 4; ++r) {
                const float s = acc[m][n][r];
                const float mm = quadmax(s);
                const float d = s - mm;
                if (dfrag) {
                    const float dp = __expf(d);
                    if (ik) {
                        if (r != (lane & 3)) psum += dp;        // j != l
                    } else {
                        nsum += fmaxf(dp * dp, 1e-8f);
                    }
                } else {
                    nsum += fmaxf(__expf(d + d), 1e-8f);
                }
            }
            // transposed side (off-diag tiles): l'-group = the 4 regs (rows)
            if (!diag) {
                const float mm2 = fmaxf(fmaxf(acc[m][n][0], acc[m][n][1]),
                                        fmaxf(acc[m][n][2], acc[m][n][3]));
#pragma unroll
                for (int r = 0; r < 4; ++r) {
                    const float d = acc[m][n][r] - mm2;
                    nsum += fmaxf(__expf(d + d), 1e-8f);
                }
            }
        }
    }

    float contrib = C_NEG * nsum - C_POS * psum;

    // block reduction -> one atomic per block
#pragma unroll
    for (int off = 32; off; off >>= 1) contrib += __shfl_down(contrib, off);
    if ((tid & 63) == 0) wsum[tid >> 6] = contrib;
    __syncthreads();
    if (tid == 0) atomicAdd(out, wsum[0] + wsum[1] + wsum[2] + wsum[3]);
}

extern "C" void kernel_launch(void* const* d_in, const int* in_sizes, int n_in,
                              void* d_out, int out_size, void* d_ws, size_t ws_size,
                              hipStream_t stream) {
    const float* A = (const float*)d_in[0];
    float* out = (float*)d_out;
    __bf16* W = (__bf16*)d_ws;                 // 8192*256*2 = 4 MB (ws is >= this)
    hipMemsetAsync(out, 0, sizeof(float), stream);
    cvt_bf16<<<(PD * KB / 8) / 256, 256, 0, stream>>>(A, W);
    dim3 grid(65, 32);                          // exactly the 2080 upper-triangle tiles
    evd_mfma<<<grid, 256, 0, stream>>>(W, out);
}

// Round 5
// 98.961 us; speedup vs baseline: 1.5067x; 1.0372x over previous
//
#include <hip/hip_runtime.h>

// EVDLoRA loss: a[2048,4,256] f32 -> scalar.
// A = [8192][256] f32 -> W bf16 (cvt kernel, also zeroes out). S = A A^T via
// bf16 MFMA, K=256. (bf16 rounding error in S washes out in the 68M-term mean;
// validated r2-r4, absmax 0.0.)
// Per (i,k,j): max over l, dp=exp(s-max);
//   i!=k: nsum += fmax(dp^2,1e-8) ; i==k: psum += dp over l!=j.
// loss = sum_blocks (C_NEG*nsum - C_POS*psum), one atomic per block.
// Upper-triangle 128x128 tiles; off-diag tiles do both orientations.
// K-loop: double-buffered LDS, prefetch distance 2, counted s_waitcnt vmcnt(4)
// (never drain-0 until last tile) + raw s_barrier — T3/T4 discipline.

#define PD   8192
#define KB   256          // K in bf16 elements
#define BM   128
#define BK   32           // bf16 K-cols per iteration (= one MFMA K-step)
#define NIT  (KB / BK)    // 8

typedef __bf16 bf16x8 __attribute__((ext_vector_type(8)));
typedef float f32x4 __attribute__((ext_vector_type(4)));

__device__ __forceinline__ void gload16(const void* g, void* l) {
    __builtin_amdgcn_global_load_lds(
        (const __attribute__((address_space(1))) unsigned int*)g,
        (__attribute__((address_space(3))) unsigned int*)l, 16, 0, 0);
}

__device__ __forceinline__ int swz(int row) { return ((row >> 1) & 3) << 4; }

// max over the 4 lanes of a quad via DPP quad_perm
__device__ __forceinline__ float quadmax(float x) {
    int v = __builtin_amdgcn_mov_dpp(__builtin_bit_cast(int, x), 0xB1, 0xF, 0xF, true); // [1,0,3,2]
    float m = fmaxf(x, __builtin_bit_cast(float, v));
    v = __builtin_amdgcn_mov_dpp(__builtin_bit_cast(int, m), 0x4E, 0xF, 0xF, true);     // [2,3,0,1]
    return fmaxf(m, __builtin_bit_cast(float, v));
}

// ---------------- f32 -> bf16 conversion (+ out zero-init) ----------------
__global__ __launch_bounds__(256)
void cvt_bf16(const float* __restrict__ A, __bf16* __restrict__ W,
              float* __restrict__ out) {
    const int idx = blockIdx.x * 256 + threadIdx.x;      // 8 floats per thread
    if (idx == 0) *out = 0.f;                            // replaces memset dispatch
    const float4 v0 = reinterpret_cast<const float4*>(A)[idx * 2];
    const float4 v1 = reinterpret_cast<const float4*>(A)[idx * 2 + 1];
    bf16x8 h;
    h[0] = (__bf16)v0.x; h[1] = (__bf16)v0.y; h[2] = (__bf16)v0.z; h[3] = (__bf16)v0.w;
    h[4] = (__bf16)v1.x; h[5] = (__bf16)v1.y; h[6] = (__bf16)v1.z; h[7] = (__bf16)v1.w;
    *reinterpret_cast<bf16x8*>(W + (size_t)idx * 8) = h;
}

// ---------------- MFMA main kernel ----------------
__global__ __launch_bounds__(256)
void evd_mfma(const __bf16* __restrict__ W, float* __restrict__ out)
{
    __shared__ __bf16 lds[2][2][BM * BK];    // [buf][op][row*32 + col], 8 KB each
    __shared__ float wsum[4];

    // triangular tile decode: grid (65, 32) -> all (bi, bk>=bi) of 64x64 tiles
    const int x = blockIdx.x, y = blockIdx.y;
    int bi, bk;
    if (x < 64 - y) { bi = y;      bk = y + x; }
    else            { bi = 63 - y; bk = x - 1; }

    const int tid = threadIdx.x;
    const int lane = tid & 63, wid = tid >> 6;
    const int wr = wid >> 1, wc = wid & 1;               // 2x2 waves, 64x64 each
    const int row0 = bi * BM, col0 = bk * BM;

    // ---- staging addresses (per thread: 2 rows x 16B per op) ----
    const int r0 = tid >> 2;                  // rows 0..63   (issue 0)
    const int r1 = 64 + r0;                   // rows 64..127 (issue 1)
    const int x0 = (tid & 3) * 16;            // 16B unit within 64B row
    const int ga0 = r0 * (KB * 2) + (x0 ^ swz(r0));
    const int ga1 = r1 * (KB * 2) + (x0 ^ swz(r1));
    const char* gAb = (const char*)(W + (size_t)row0 * KB);
    const char* gBb = (const char*)(W + (size_t)col0 * KB);
    const int ldsOff0 = wid * 1024;           // wave-uniform LDS dest bases
    const int ldsOff1 = 4096 + wid * 1024;

    // ---- fragment read offsets (swizzled), loop-invariant ----
    const int fr = lane & 15, kq = lane >> 4;
    int aOff[4], bOff[4];
#pragma unroll
    for (int m = 0; m < 4; ++m) {
        const int ra = wr * 64 + m * 16 + fr;
        const int rb = wc * 64 + m * 16 + fr;
        aOff[m] = ra * 64 + ((kq * 16) ^ swz(ra));
        bOff[m] = rb * 64 + ((kq * 16) ^ swz(rb));
    }

    f32x4 acc[4][4];
#pragma unroll
    for (int m = 0; m < 4; ++m)
#pragma unroll
        for (int n = 0; n < 4; ++n)
#pragma unroll
            for (int q = 0; q < 4; ++q) acc[m][n][q] = 0.f;

    // stage tile t (4 gload16) into buffer b
    auto stage = [&](int t, int b) {
        const int kbyte = t * (BK * 2);
        char* dA = (char*)&lds[b][0][0];
        char* dB = (char*)&lds[b][1][0];
        gload16(gAb + ga0 + kbyte, dA + ldsOff0);
        gload16(gAb + ga1 + kbyte, dA + ldsOff1);
        gload16(gBb + ga0 + kbyte, dB + ldsOff0);
        gload16(gBb + ga1 + kbyte, dB + ldsOff1);
    };

    // prologue: 2 tiles in flight
    stage(0, 0);
    stage(1, 1);

#pragma unroll
    for (int t = 0; t < NIT; ++t) {
        // tile t's 4 loads are the oldest; keep tile t+1's 4 in flight
        if (t == NIT - 1) asm volatile("s_waitcnt vmcnt(0)" ::: "memory");
        else              asm volatile("s_waitcnt vmcnt(4)" ::: "memory");
        __builtin_amdgcn_s_barrier();          // tile t visible to all waves

        const char* baseA = (const char*)&lds[t & 1][0][0];
        const char* baseB = (const char*)&lds[t & 1][1][0];
        bf16x8 af[4], bfr[4];
#pragma unroll
        for (int m = 0; m < 4; ++m) {
            af[m]  = *(const bf16x8*)(baseA + aOff[m]);
            bfr[m] = *(const bf16x8*)(baseB + bOff[m]);
        }
        if (t + 2 < NIT) {
            asm volatile("s_waitcnt lgkmcnt(0)" ::: "memory");  // my reads in regs
            __builtin_amdgcn_s_barrier();                       // all waves done reading
            stage(t + 2, t & 1);                                // reuse freed buffer
        }
#pragma unroll
        for (int m = 0; m < 4; ++m)
#pragma unroll
            for (int n = 0; n < 4; ++n)
                acc[m][n] = __builtin_amdgcn_mfma_f32_16x16x32_bf16(af[m], bfr[n], acc[m][n], 0, 0, 0);
    }

    // ---------------- fused epilogue ----------------
    // C/D layout: col = lane&15, row = (lane>>4)*4 + reg
    // Pre-scale y = 2*log2(e)*s: clamp-squares become exp2(y - ymax) directly.
    const float C_NEG = 1.0f / (2048.0f * 2047.0f * 16.0f);
    const float C_POS = 2.0f / (2048.0f * 12.0f);
    const float SCL = 2.0f * 1.4426950408889634f;
    const bool diag = (bi == bk);
    const bool ik = ((lane >> 4) == ((lane & 15) >> 2));
    float nsum = 0.f, psum = 0.f;

#pragma unroll
    for (int m = 0; m < 4; ++m) {
#pragma unroll
        for (int n = 0; n < 4; ++n) {
            float yv[4];
#pragma unroll
            for (int q = 0; q < 4; ++q) yv[q] = SCL * acc[m][n][q];
            const bool dfrag = diag && (wr == wc) && (m == n);
            // row-side: l-group = 4 lanes of a quad (cols)
#pragma unroll
            for (int r = 0; r < 4; ++r) {
                const float d2 = yv[r] - quadmax(yv[r]);     // = 2*log2e*(s-mm)
                if (dfrag) {
                    const float dp = __builtin_amdgcn_exp2f(0.5f * d2);  // exp(s-mm)
                    if (ik) {
                        if (r != (lane & 3)) psum += dp;                 // j != l
                    } else {
                        nsum += fmaxf(dp * dp, 1e-8f);
                    }
                } else {
                    nsum += fmaxf(__builtin_amdgcn_exp2f(d2), 1e-8f);
                }
            }
            // transposed side (off-diag tiles): l'-group = the 4 regs (rows)
            if (!diag) {
                const float ymax = fmaxf(fmaxf(fmaxf(yv[0], yv[1]), yv[2]), yv[3]);
#pragma unroll
                for (int r = 0; r < 4; ++r)
                    nsum += fmaxf(__builtin_amdgcn_exp2f(yv[r] - ymax), 1e-8f);
            }
        }
    }

    float contrib = C_NEG * nsum - C_POS * psum;

    // block reduction -> one atomic per block
#pragma unroll
    for (int off = 32; off; off >>= 1) contrib += __shfl_down(contrib, off);
    if ((tid & 63) == 0) wsum[tid >> 6] = contrib;
    __syncthreads();
    if (tid == 0) atomicAdd(out, wsum[0] + wsum[1] + wsum[2] + wsum[3]);
}

extern "C" void kernel_launch(void* const* d_in, const int* in_sizes, int n_in,
                              void* d_out, int out_size, void* d_ws, size_t ws_size,
                              hipStream_t stream) {
    const float* A = (const float*)d_in[0];
    float* out = (float*)d_out;
    __bf16* W = (__bf16*)d_ws;                 // 8192*256*2 = 4 MB scratch
    cvt_bf16<<<(PD * KB / 8) / 256, 256, 0, stream>>>(A, W, out);
    dim3 grid(65, 32);                          // exactly the 2080 upper-triangle tiles
    evd_mfma<<<grid, 256, 0, stream>>>(W, out);
}

// Round 6
// 92.825 us; speedup vs baseline: 1.6063x; 1.0661x over previous
//
#include <hip/hip_runtime.h>

// EVDLoRA loss: a[2048,4,256] f32 -> scalar.
// A = [8192][256] f32 -> W bf16 (cvt kernel, also zeroes out). S = A A^T via
// bf16 MFMA, K=256. (bf16 rounding in S washes out in the 68M-term mean;
// validated r2-r5, absmax 0.0.)
// Per (i,k,j): max over l, dp=exp(s-max);
//   i!=k: nsum += fmax(dp^2,1e-8) ; i==k: psum += dp over l!=j.
// loss = sum_blocks (C_NEG*nsum - C_POS*psum), one atomic per block.
// Round 6: 8-wave blocks, TWO column-tiles per block sharing the A panel
// (waves 0-3 -> (bi,bkL), waves 4-7 -> (bi,bkR)). 1056 full blocks, no empties.
// Double-buffered LDS (A,B1,B2 = 24 KB/buf), counted s_waitcnt vmcnt(3),
// prefetch distance 2, setprio around MFMA, bijective XCD block swizzle.

#define PD   8192
#define KB   256          // K in bf16 elements
#define BM   128
#define BK   32           // bf16 K-cols per iteration (one MFMA K-step)
#define NIT  (KB / BK)    // 8

typedef __bf16 bf16x8 __attribute__((ext_vector_type(8)));
typedef float f32x4 __attribute__((ext_vector_type(4)));

__device__ __forceinline__ void gload16(const void* g, void* l) {
    __builtin_amdgcn_global_load_lds(
        (const __attribute__((address_space(1))) unsigned int*)g,
        (__attribute__((address_space(3))) unsigned int*)l, 16, 0, 0);
}

__device__ __forceinline__ int swz(int row) { return ((row >> 1) & 3) << 4; }

// max over the 4 lanes of a quad via DPP quad_perm
__device__ __forceinline__ float quadmax(float x) {
    int v = __builtin_amdgcn_mov_dpp(__builtin_bit_cast(int, x), 0xB1, 0xF, 0xF, true); // [1,0,3,2]
    float m = fmaxf(x, __builtin_bit_cast(float, v));
    v = __builtin_amdgcn_mov_dpp(__builtin_bit_cast(int, m), 0x4E, 0xF, 0xF, true);     // [2,3,0,1]
    return fmaxf(m, __builtin_bit_cast(float, v));
}

// ---------------- f32 -> bf16 conversion (+ out zero-init) ----------------
__global__ __launch_bounds__(256)
void cvt_bf16(const float* __restrict__ A, __bf16* __restrict__ W,
              float* __restrict__ out) {
    const int idx = blockIdx.x * 256 + threadIdx.x;      // 8 floats per thread
    if (idx == 0) *out = 0.f;                            // replaces memset dispatch
    const float4 v0 = reinterpret_cast<const float4*>(A)[idx * 2];
    const float4 v1 = reinterpret_cast<const float4*>(A)[idx * 2 + 1];
    bf16x8 h;
    h[0] = (__bf16)v0.x; h[1] = (__bf16)v0.y; h[2] = (__bf16)v0.z; h[3] = (__bf16)v0.w;
    h[4] = (__bf16)v1.x; h[5] = (__bf16)v1.y; h[6] = (__bf16)v1.z; h[7] = (__bf16)v1.w;
    *reinterpret_cast<bf16x8*>(W + (size_t)idx * 8) = h;
}

// ---------------- MFMA main kernel (8 waves, 2 tiles/block) ----------------
__global__ __launch_bounds__(512)
void evd_mfma(const __bf16* __restrict__ W, float* __restrict__ out)
{
    __shared__ __bf16 lds[2][3][BM * BK];   // [buf][A,B1,B2], 8 KB each slab
    __shared__ float wsum[8];

    // ---- block decode: 1056 blocks -> (bi, pair px), no empty blocks ----
    // nid flattened over grid(33,16,2); m204 bijective XCD swizzle (1056 = 8*132)
    const int nid = (blockIdx.z * gridDim.y + blockIdx.y) * gridDim.x + blockIdx.x;
    const int id  = (nid & 7) * 132 + (nid >> 3);
    const int xx  = id % 33;                 // 0..32
    const int yzq = id / 33;                 // 0..31
    const int yy  = yzq & 15;                // 0..15 (complementary row-pair)
    const int zz  = yzq >> 4;                // 0/1
    int rp, px;
    if (xx < 32 - yy) { rp = yy;      px = xx; }
    else              { rp = 31 - yy; px = xx - (32 - yy); }
    const int bi  = 2 * rp + zz;             // row tile 0..63, px < 32-rp
    const int bkL = bi + 2 * px;
    int bkR = bkL + 1;
    const bool validR = (bkR < 64);
    if (!validR) bkR = bkL;                  // clip: waves 4-7 duplicate L, masked

    const int tid = threadIdx.x;
    const int lane = tid & 63, w = tid >> 6;     // 8 waves
    const int g = w >> 2;                        // 0: tile L, 1: tile R
    const int sub = w & 3, wr = sub >> 1, wc = sub & 1;   // 2x2 within tile
    const int row0 = bi * BM;
    const int bk   = g ? bkR : bkL;
    const int col0 = bk * BM;
    const bool valid = g ? validR : true;

    // ---- staging addresses ----
    // A: every thread 1 load (512 x 16B = 8 KB panel)
    const int ar = tid >> 2;
    const int ax = (tid & 3) * 16;
    const int gaA = (row0 + ar) * (KB * 2) + (ax ^ swz(ar));
    // B: each 256-thread half stages its own 8 KB panel (2 loads/thread)
    const int t2  = tid & 255;
    const int br0 = t2 >> 2, br1 = 64 + br0;
    const int bx  = (t2 & 3) * 16;
    const int colB = (w < 4 ? bkL : bkR) * BM;
    const int gaB0 = (colB + br0) * (KB * 2) + (bx ^ swz(br0));
    const int gaB1 = (colB + br1) * (KB * 2) + (bx ^ swz(br1));
    const char* gW = (const char*)W;
    // wave-uniform LDS dest bases (HW adds lane*16)
    const int dA = w * 1024;                          // A slab
    const int dB = 8192 + g * 8192 + (w & 3) * 1024;  // B1 or B2 slab

    // ---- fragment read offsets (swizzled), loop-invariant ----
    const int fr = lane & 15, kq = lane >> 4;
    int aOff[4], bOff[4];
#pragma unroll
    for (int m = 0; m < 4; ++m) {
        const int ra = wr * 64 + m * 16 + fr;
        const int rb = wc * 64 + m * 16 + fr;
        aOff[m] = ra * 64 + ((kq * 16) ^ swz(ra));
        bOff[m] = 8192 + g * 8192 + rb * 64 + ((kq * 16) ^ swz(rb));
    }

    f32x4 acc[4][4];
#pragma unroll
    for (int m = 0; m < 4; ++m)
#pragma unroll
        for (int n = 0; n < 4; ++n)
#pragma unroll
            for (int q = 0; q < 4; ++q) acc[m][n][q] = 0.f;

    // stage tile t (3 gload16 per wave) into buffer b
    auto stage = [&](int t, int b) {
        const int kb2 = t * (BK * 2);
        char* base = (char*)&lds[b][0][0];
        gload16(gW + gaA  + kb2, base + dA);
        gload16(gW + gaB0 + kb2, base + dB);
        gload16(gW + gaB1 + kb2, base + dB + 4096);
    };

    // prologue: 2 tiles in flight (6 loads/wave outstanding)
    stage(0, 0);
    stage(1, 1);

#pragma unroll
    for (int t = 0; t < NIT; ++t) {
        // tile t's 3 loads are the oldest; keep tile t+1's 3 in flight
        if (t == NIT - 1) asm volatile("s_waitcnt vmcnt(0)" ::: "memory");
        else              asm volatile("s_waitcnt vmcnt(3)" ::: "memory");
        __builtin_amdgcn_s_barrier();          // tile t visible to all waves

        const char* base = (const char*)&lds[t & 1][0][0];
        bf16x8 af[4], bfr[4];
#pragma unroll
        for (int m = 0; m < 4; ++m) {
            af[m]  = *(const bf16x8*)(base + aOff[m]);
            bfr[m] = *(const bf16x8*)(base + bOff[m]);
        }
        if (t + 2 < NIT) {
            asm volatile("s_waitcnt lgkmcnt(0)" ::: "memory");  // frags in regs
            __builtin_amdgcn_s_barrier();                       // all waves done reading
            stage(t + 2, t & 1);                                // reuse freed buffer
        }
        __builtin_amdgcn_s_setprio(1);
#pragma unroll
        for (int m = 0; m < 4; ++m)
#pragma unroll
            for (int n = 0; n < 4; ++n)
                acc[m][n] = __builtin_amdgcn_mfma_f32_16x16x32_bf16(af[m], bfr[n], acc[m][n], 0, 0, 0);
        __builtin_amdgcn_s_setprio(0);
    }

    // ---------------- fused epilogue ----------------
    // C/D layout: col = lane&15, row = (lane>>4)*4 + reg
    // Pre-scale y = 2*log2(e)*s: clamp-squares become exp2(y - ymax) directly.
    const float C_NEG = 1.0f / (2048.0f * 2047.0f * 16.0f);
    const float C_POS = 2.0f / (2048.0f * 12.0f);
    const float SCL = 2.0f * 1.4426950408889634f;
    const bool diag = (bi == bk);
    const bool ik = ((lane >> 4) == ((lane & 15) >> 2));
    float nsum = 0.f, psum = 0.f;

#pragma unroll
    for (int m = 0; m < 4; ++m) {
#pragma unroll
        for (int n = 0; n < 4; ++n) {
            float yv[4];
#pragma unroll
            for (int q = 0; q < 4; ++q) yv[q] = SCL * acc[m][n][q];
            const bool dfrag = diag && (wr == wc) && (m == n);
            // row-side: l-group = 4 lanes of a quad (cols)
#pragma unroll
            for (int r = 0; r < 4; ++r) {
                const float d2 = yv[r] - quadmax(yv[r]);     // = 2*log2e*(s-mm)
                if (dfrag) {
                    const float dp = __builtin_amdgcn_exp2f(0.5f * d2);  // exp(s-mm)
                    if (ik) {
                        if (r != (lane & 3)) psum += dp;                 // j != l
                    } else {
                        nsum += fmaxf(dp * dp, 1e-8f);
                    }
                } else {
                    nsum += fmaxf(__builtin_amdgcn_exp2f(d2), 1e-8f);
                }
            }
            // transposed side (off-diag tiles): l'-group = the 4 regs (rows)
            if (!diag) {
                const float ymax = fmaxf(fmaxf(fmaxf(yv[0], yv[1]), yv[2]), yv[3]);
#pragma unroll
                for (int r = 0; r < 4; ++r)
                    nsum += fmaxf(__builtin_amdgcn_exp2f(yv[r] - ymax), 1e-8f);
            }
        }
    }

    float contrib = valid ? (C_NEG * nsum - C_POS * psum) : 0.f;

    // block reduction -> one atomic per block
#pragma unroll
    for (int off = 32; off; off >>= 1) contrib += __shfl_down(contrib, off);
    if (lane == 0) wsum[w] = contrib;
    __syncthreads();
    if (tid == 0) {
        float s = 0.f;
#pragma unroll
        for (int i = 0; i < 8; ++i) s += wsum[i];
        atomicAdd(out, s);
    }
}

extern "C" void kernel_launch(void* const* d_in, const int* in_sizes, int n_in,
                              void* d_out, int out_size, void* d_ws, size_t ws_size,
                              hipStream_t stream) {
    const float* A = (const float*)d_in[0];
    float* out = (float*)d_out;
    __bf16* W = (__bf16*)d_ws;                 // 8192*256*2 = 4 MB scratch
    cvt_bf16<<<(PD * KB / 8) / 256, 256, 0, stream>>>(A, W, out);
    dim3 grid(33, 16, 2);                       // 1056 blocks = all tile-pairs
    evd_mfma<<<grid, 512, 0, stream>>>(W, out);
}